// Round 1
// baseline (248.080 us; speedup 1.0000x reference)
//
#include <hip/hip_runtime.h>
#include <hip/hip_bf16.h>

#define D   768
#define NQ  16      // q groups
#define NP  128     // p groups
#define QI  64      // q vectors per group
#define PJ  256     // p vectors per group
#define MQ  (NQ*QI)   // 1024 query vectors
#define MP  (NP*PJ)   // 32768 passage vectors

typedef __attribute__((ext_vector_type(8))) short  short8;   // 8 x bf16 (4 VGPRs)
typedef __attribute__((ext_vector_type(4))) float  floatx4;  // MFMA acc

// ---------------------------------------------------------------------------
// Kernel 1/2: row-wise L2 normalize fp32 -> bf16.  One block (256 thr) per row.
// 768 = 256*3 elements per row.
// ---------------------------------------------------------------------------
__global__ __launch_bounds__(256) void norm_rows(const float* __restrict__ in,
                                                 ushort* __restrict__ out) {
    const int row  = blockIdx.x;
    const float* r = in + (size_t)row * D;
    const int t    = threadIdx.x;
    const int wave = t >> 6, lane = t & 63;

    float x0 = r[t], x1 = r[t + 256], x2 = r[t + 512];
    float ss = x0*x0 + x1*x1 + x2*x2;
    #pragma unroll
    for (int o = 32; o > 0; o >>= 1) ss += __shfl_xor(ss, o, 64);

    __shared__ float sm[4];
    if (lane == 0) sm[wave] = ss;
    __syncthreads();
    float tot = sm[0] + sm[1] + sm[2] + sm[3];
    float inv = 1.0f / fmaxf(sqrtf(tot), 1e-12f);

    __hip_bfloat16 b0 = __float2bfloat16(x0 * inv);
    __hip_bfloat16 b1 = __float2bfloat16(x1 * inv);
    __hip_bfloat16 b2 = __float2bfloat16(x2 * inv);
    ushort* o_ = out + (size_t)row * D;
    o_[t]       = *(ushort*)&b0;
    o_[t + 256] = *(ushort*)&b1;
    o_[t + 512] = *(ushort*)&b2;
}

// ---------------------------------------------------------------------------
// Kernel 3: per (q,p) pair, compute the 64x256 block of Qn·Pn^T with bf16 MFMA
// and reduce to a single max -> mv[q][p].
// Block = 256 thr (4 waves).  Wave w covers all 64 Q-rows x 64 P-rows
// [w*64, w*64+64).  K staged in LDS, BK=64, +8 bf16 pad (2-way conflicts only).
// Note: block-max makes MFMA C/D layout and k-permutations correctness-
// irrelevant — every acc element is some dot(qn_i, pn_j) in the block.
// ---------------------------------------------------------------------------
#define BK  64
#define LDA 72   // 64 + 8 pad (bf16 elems); 144 B row stride = 9*16 B
#define LDB 72

__global__ __launch_bounds__(256) void sim_max_kernel(const ushort* __restrict__ Qn,
                                                      const ushort* __restrict__ Pn,
                                                      float* __restrict__ mv) {
    const int p = blockIdx.x, q = blockIdx.y;
    __shared__ ushort lA[QI * LDA];   // 9216 B
    __shared__ ushort lB[PJ * LDB];   // 36864 B
    __shared__ float  smax[4];

    const int t = threadIdx.x;
    const int wave = t >> 6, lane = t & 63;
    const int quad = lane >> 4, r = lane & 15;

    const ushort* Abase = Qn + (size_t)q * QI * D;
    const ushort* Bbase = Pn + (size_t)p * PJ * D;

    floatx4 acc[4][4];
    #pragma unroll
    for (int i = 0; i < 4; i++)
        #pragma unroll
        for (int j = 0; j < 4; j++) acc[i][j] = (floatx4){0.f, 0.f, 0.f, 0.f};

    for (int k0 = 0; k0 < D; k0 += BK) {
        __syncthreads();   // protect LDS from previous iteration's readers
        // stage A: 64x64 bf16, 8 bf16 (16 B) per thread x 2
        #pragma unroll
        for (int c = 0; c < 2; c++) {
            int flat = (t + c * 256) * 8;
            int row = flat >> 6, col = flat & 63;
            float4 v = *(const float4*)(Abase + (size_t)row * D + k0 + col);
            *(float4*)(lA + row * LDA + col) = v;
        }
        // stage B: 256x64 bf16, 8 chunks per thread
        #pragma unroll
        for (int c = 0; c < 8; c++) {
            int flat = (t + c * 256) * 8;
            int row = flat >> 6, col = flat & 63;
            float4 v = *(const float4*)(Bbase + (size_t)row * D + k0 + col);
            *(float4*)(lB + row * LDB + col) = v;
        }
        __syncthreads();

        #pragma unroll
        for (int ks = 0; ks < 2; ks++) {
            const int koff = ks * 32 + quad * 8;
            short8 a[4], b[4];
            #pragma unroll
            for (int i = 0; i < 4; i++)
                a[i] = *(const short8*)(lA + (i * 16 + r) * LDA + koff);
            #pragma unroll
            for (int j = 0; j < 4; j++)
                b[j] = *(const short8*)(lB + (wave * 64 + j * 16 + r) * LDB + koff);
            #pragma unroll
            for (int i = 0; i < 4; i++)
                #pragma unroll
                for (int j = 0; j < 4; j++)
                    acc[i][j] = __builtin_amdgcn_mfma_f32_16x16x32_bf16(
                        a[i], b[j], acc[i][j], 0, 0, 0);
        }
    }

    // max over this lane's 64 accumulator values
    float m = -1e30f;
    #pragma unroll
    for (int i = 0; i < 4; i++)
        #pragma unroll
        for (int j = 0; j < 4; j++)
            #pragma unroll
            for (int e = 0; e < 4; e++) m = fmaxf(m, acc[i][j][e]);
    #pragma unroll
    for (int o = 32; o > 0; o >>= 1) m = fmaxf(m, __shfl_xor(m, o, 64));
    if (lane == 0) smax[wave] = m;
    __syncthreads();
    if (t == 0)
        mv[q * NP + p] = fmaxf(fmaxf(smax[0], smax[1]), fmaxf(smax[2], smax[3]));
}

// ---------------------------------------------------------------------------
// Kernel 4: scores[q][p] = dot(q_hidden[q,0,:], p_hidden[p,0,:]) in fp32.
// One wave per (q,p).
// ---------------------------------------------------------------------------
__global__ __launch_bounds__(64) void scores_kernel(const float* __restrict__ qh,
                                                    const float* __restrict__ ph,
                                                    float* __restrict__ scores) {
    const int bid = blockIdx.x;           // 0..2047
    const int q = bid >> 7, p = bid & 127;
    const float* qr = qh + (size_t)q * QI * D;   // q_hidden[q, 0, :]
    const float* pr = ph + (size_t)p * PJ * D;   // p_hidden[p, 0, :]
    const int lane = threadIdx.x;
    float s = 0.f;
    #pragma unroll
    for (int k = 0; k < D / 64; k++) s += qr[lane + k * 64] * pr[lane + k * 64];
    #pragma unroll
    for (int o = 32; o > 0; o >>= 1) s += __shfl_xor(s, o, 64);
    if (lane == 0) scores[q * NP + p] = s;
}

// ---------------------------------------------------------------------------
// Kernel 5: final loss.  One wave; lane handles columns {lane, lane+64}.
// loss = 0.5*(0.3*(CE_s + KLD_mv + CE_inter) + 0.2*(KLD_s + KLD_mv))
// (reference's CE(mv_scores) is dead code — overwritten by the KLD)
// ---------------------------------------------------------------------------
__global__ __launch_bounds__(64) void loss_kernel(const float* __restrict__ scores,
                                                  const float* __restrict__ mv,
                                                  float* __restrict__ out) {
    const int lane = threadIdx.x;
    float ce_s = 0.f, ce_t = 0.f, kld_s = 0.f, kld_m = 0.f;

    for (int q = 0; q < NQ; q++) {
        const float* srow = scores + q * NP;
        const float* mrow = mv + q * NP;
        float s0 = srow[lane], s1 = srow[lane + 64];
        float m0 = mrow[lane], m1 = mrow[lane + 64];
        float t0 = s0 + 0.3f * m0, t1 = s1 + 0.3f * m1;

        float xs = fmaxf(s0, s1), xm = fmaxf(m0, m1), xt = fmaxf(t0, t1);
        #pragma unroll
        for (int o = 32; o > 0; o >>= 1) {
            xs = fmaxf(xs, __shfl_xor(xs, o, 64));
            xm = fmaxf(xm, __shfl_xor(xm, o, 64));
            xt = fmaxf(xt, __shfl_xor(xt, o, 64));
        }
        float es = expf(s0 - xs) + expf(s1 - xs);
        float em = expf(m0 - xm) + expf(m1 - xm);
        float et = expf(t0 - xt) + expf(t1 - xt);
        #pragma unroll
        for (int o = 32; o > 0; o >>= 1) {
            es += __shfl_xor(es, o, 64);
            em += __shfl_xor(em, o, 64);
            et += __shfl_xor(et, o, 64);
        }
        float lse_s = xs + logf(es), lse_m = xm + logf(em), lse_t = xt + logf(et);

        float ls0 = s0 - lse_s, ls1 = s1 - lse_s;
        float lm0 = m0 - lse_m, lm1 = m1 - lse_m;
        float lt0 = t0 - lse_t, lt1 = t1 - lse_t;
        float pt0 = expf(lt0), pt1 = expf(lt1);
        kld_s += pt0 * (lt0 - ls0) + pt1 * (lt1 - ls1);
        kld_m += pt0 * (lt0 - lm0) + pt1 * (lt1 - lm1);

        const int tgt = q * (NP / NQ);     // q*8
        if (lane == (tgt & 63)) {
            if (tgt < 64) { ce_s -= ls0; ce_t -= lt0; }
            else          { ce_s -= ls1; ce_t -= lt1; }
        }
    }
    #pragma unroll
    for (int o = 32; o > 0; o >>= 1) {
        ce_s  += __shfl_xor(ce_s, o, 64);
        ce_t  += __shfl_xor(ce_t, o, 64);
        kld_s += __shfl_xor(kld_s, o, 64);
        kld_m += __shfl_xor(kld_m, o, 64);
    }
    if (lane == 0) {
        ce_s /= 16.f; ce_t /= 16.f; kld_s /= 16.f; kld_m /= 16.f;
        float L1 = 0.3f * (ce_s + kld_m + ce_t);
        float L2 = 0.2f * (kld_s + kld_m);
        out[0] = 0.5f * (L1 + L2);
    }
}

// ---------------------------------------------------------------------------
extern "C" void kernel_launch(void* const* d_in, const int* in_sizes, int n_in,
                              void* d_out, int out_size, void* d_ws, size_t ws_size,
                              hipStream_t stream) {
    const float* qh = (const float*)d_in[0];   // (16, 64, 768) fp32
    const float* ph = (const float*)d_in[1];   // (128, 256, 768) fp32

    // workspace layout (~52 MB): Pn bf16 | Qn bf16 | mv f32 | scores f32
    char* ws = (char*)d_ws;
    ushort* Pn = (ushort*)ws;
    ushort* Qn = (ushort*)(ws + (size_t)MP * D * sizeof(ushort));
    float*  mv = (float*)(ws + (size_t)MP * D * sizeof(ushort)
                             + (size_t)MQ * D * sizeof(ushort));
    float* scores = mv + NQ * NP;

    norm_rows<<<MP, 256, 0, stream>>>(ph, Pn);
    norm_rows<<<MQ, 256, 0, stream>>>(qh, Qn);
    sim_max_kernel<<<dim3(NP, NQ), 256, 0, stream>>>(Qn, Pn, mv);
    scores_kernel<<<NQ * NP, 64, 0, stream>>>(qh, ph, scores);
    loss_kernel<<<1, 64, 0, stream>>>(scores, mv, (float*)d_out);
}